// Round 7
// baseline (285.191 us; speedup 1.0000x reference)
//
#include <hip/hip_runtime.h>
#include <math.h>

// QueryEmb: B=4,L=512,D=512,V=32000, 4 segments of 8000, TEMP=sqrt(512).
// Equivalences: (1) masked softmax == softmax over token's own segment only;
// (2) |scores|<=~0.35 -> exp() safe without max-subtraction -> plain-sum
//     denominators AND trivially split-K-able PV (no flash rescaling).
// R7: FUSED flash kernel replaces k_qk + k_pv + P-matrix: per (32-slot tile,
// 800-row split): loop 32-row chunks { stage E(QK layout)+ET(PV layout) via
// global_load_lds; S^T=E.Q^T (Q in regs); exp -> sP (LDS, A-layout); O +=
// P.E via sET }. O accumulated in regs, merged across splits by atomicAdd
// (R4 measured distinct-address atomics ~free). Kills 87 MB of P traffic and
// the second GEMM's staging pass entirely.

constexpr int Dm   = 512;
constexpr int SEG  = 8000;
constexpr int NTOK = 2048;
constexpr int TT   = 32;              // slot tile
constexpr int MAXT = 68;              // 2048/32 + 4 pad tiles
constexpr int MAXSLOTS = MAXT * TT;   // 2176
constexpr int RS   = 10;              // row splits: 800 rows each
constexpr int CH   = 32;              // chunk rows
constexpr int CHUNKS = 25;            // 800/32

// ws layout (bytes)
constexpr size_t WS_DENOM = 0;                         // 2048 f32
constexpr size_t WS_META  = 8192;                      // 8 int
constexpr size_t WS_PERM  = 8448;                      // 2176 int
constexpr size_t WS_QB    = 32768;                     // bf16 [2176][512]
constexpr size_t WS_OACC  = WS_QB + (size_t)MAXSLOTS * Dm * 2;        // f32 [2176][512]
constexpr size_t WS_EB    = WS_OACC + (size_t)MAXSLOTS * Dm * 4;      // bf16 [32000][512]
constexpr size_t WS_ET    = WS_EB + (size_t)32000 * Dm * 2;           // bf16 [512][32000]
// total ~72.3 MB

typedef __attribute__((ext_vector_type(8))) short bf16x8;
typedef __attribute__((ext_vector_type(4))) float f32x4;

static __device__ __forceinline__ ushort f2bf(float f) {
    union { float f; unsigned u; } v; v.f = f;
    unsigned r = v.u + 0x7FFF + ((v.u >> 16) & 1);   // RNE
    return (ushort)(r >> 16);
}

// async global(16B/lane, per-lane gptr) -> LDS(wave-uniform base + lane*16)
static __device__ __forceinline__ void gll16(const void* g, void* l) {
    __builtin_amdgcn_global_load_lds(
        (const __attribute__((address_space(1))) unsigned int*)g,
        (__attribute__((address_space(3))) unsigned int*)l, 16, 0, 0);
}

// ---- K1: sort tokens by rank into 32-padded slot regions (1 block) ----
__global__ __launch_bounds__(256)
void k_prep(const int* __restrict__ xr, int* __restrict__ meta, int* __restrict__ perm,
            float* __restrict__ denom) {
    __shared__ int cnt[4], base[5], cur[4];
    const int tid = threadIdx.x;
    if (tid < 4) { cnt[tid] = 0; cur[tid] = 0; }
    __syncthreads();
    for (int t = tid; t < NTOK; t += 256) {
        atomicAdd(&cnt[xr[t]], 1);
        denom[t] = 0.f;
    }
    __syncthreads();
    if (tid == 0) {
        base[0] = 0;
        for (int r = 0; r < 4; ++r) base[r+1] = base[r] + ((cnt[r] + TT - 1) / TT) * TT;
        for (int r = 0; r < 5; ++r) meta[r] = base[r];
    }
    __syncthreads();
    for (int s = tid; s < MAXSLOTS; s += 256) perm[s] = -1;
    __syncthreads();
    for (int t = tid; t < NTOK; t += 256) {
        int r = xr[t];
        perm[base[r] + atomicAdd(&cur[r], 1)] = t;
    }
}

// ---- K2: emb fp32 [32000][512] -> EB bf16 (row-major) + ET bf16 (transposed) ----
__global__ __launch_bounds__(256)
void k_conv(const float* __restrict__ emb, ushort* __restrict__ EB, ushort* __restrict__ ET) {
    __shared__ ushort sT[64 * 64];
    const int tid = threadIdx.x;
    const int r0 = blockIdx.x * 64, d0 = blockIdx.y * 64;
    {
        const int r = tid >> 2, cq = tid & 3;
        const float* src = emb + (size_t)(r0 + r) * Dm + d0 + cq * 16;
        ushort* dst = EB + (size_t)(r0 + r) * Dm + d0 + cq * 16;
        #pragma unroll
        for (int k = 0; k < 4; ++k) {
            float4 v = ((const float4*)src)[k];
            ushort4 u; u.x=f2bf(v.x); u.y=f2bf(v.y); u.z=f2bf(v.z); u.w=f2bf(v.w);
            ((ushort4*)dst)[k] = u;
            #pragma unroll
            for (int j = 0; j < 4; ++j) {
                int dq = cq * 16 + k * 4 + j;
                ushort val = (j==0)?u.x:(j==1)?u.y:(j==2)?u.z:u.w;
                sT[(dq * 8 + ((r >> 3) ^ (dq & 7))) * 8 + (r & 7)] = val;
            }
        }
    }
    __syncthreads();
    {
        const int d = tid >> 2, rq = tid & 3;
        ushort* dst = ET + (size_t)(d0 + d) * 32000 + r0 + rq * 16;
        #pragma unroll
        for (int b = 0; b < 2; ++b)
            ((uint4*)dst)[b] = *(const uint4*)(sT + (d * 8 + (((rq*2+b)) ^ (d & 7))) * 8);
    }
}

// ---- K2b: gather Q -> Qb bf16 [2176 slots][512] (pad slots zeroed) ----
__global__ __launch_bounds__(256)
void k_qb(const float* __restrict__ q, const int* __restrict__ perm, ushort* __restrict__ Qb) {
    const int s0 = blockIdx.x * 64, tid = threadIdx.x;
    for (int j = 0; j < 32; ++j) {
        int f = j * 256 + tid;
        int sl = f >> 7, c4 = f & 127;
        int tok = perm[s0 + sl];
        ushort4 u;
        if (tok >= 0) {
            float4 v = ((const float4*)q)[(size_t)tok * 128 + c4];
            u.x=f2bf(v.x); u.y=f2bf(v.y); u.z=f2bf(v.z); u.w=f2bf(v.w);
        } else { u.x = u.y = u.z = u.w = 0; }
        ((ushort4*)(Qb + (size_t)(s0 + sl) * Dm))[c4] = u;
    }
}

// ---- K3: fused QK -> exp -> PV over one (slot-tile, row-split) ----
// Waves: rowh=w>>1 (QK row half), sloth=w&1 (QK slot half), d-strip = w*128.
__global__ __launch_bounds__(256)
void k_fused(const ushort* __restrict__ EB, const ushort* __restrict__ ET,
             const ushort* __restrict__ Qb, const int* __restrict__ meta,
             const int* __restrict__ perm, float* __restrict__ denom,
             float* __restrict__ Oacc) {
    __shared__ ushort sE[CH * Dm];    // 32 KB: granule (row,c) at row*64 + (c^(row&7) low3)
    __shared__ ushort sET[CH * Dm];   // 32 KB: unit-swizzled [d-pair][8 granules]; sQ alias in prologue
    __shared__ ushort sP[TT * 36];    // 2.25 KB: [slot][32 rows + 4 pad]

    const int tid = threadIdx.x, lane = tid & 63, w = tid >> 6;
    const int split = blockIdx.x / MAXT;
    const int tt    = blockIdx.x % MAXT;
    const int slot0 = tt * TT;
    const int b1 = meta[1], b2 = meta[2], b3 = meta[3], b4 = meta[4];
    if (slot0 >= b4) return;
    const int rank = (slot0 >= b1) + (slot0 >= b2) + (slot0 >= b3);

    const int quad = lane >> 4, l15 = lane & 15;
    const int rowh = w >> 1, sloth = w & 1;

    // ---- prologue: stage Q tile (plain [32][512]) into sET space, preload B-frags
    #pragma unroll
    for (int i = 0; i < 8; ++i) {
        int row = w * 8 + i;
        gll16(Qb + (size_t)(slot0 + row) * Dm + lane * 8, sET + row * Dm);
    }
    __syncthreads();
    bf16x8 Bq[16];
    #pragma unroll
    for (int ks = 0; ks < 16; ++ks)
        Bq[ks] = *(const bf16x8*)(sET + (sloth * 16 + l15) * Dm + ks * 32 + quad * 8);
    __syncthreads();   // sET free for reuse

    // per-lane constant for sET staging: lane L -> source (dlocal0, g)
    const int sst = (lane & 7) ^ ((lane >> 3) & 7);       // s, lane-const
    const int dl0 = ((lane >> 3) << 1) + (sst >> 2);
    const int gst = sst & 3;
    const ushort* EBseg = EB + (size_t)rank * SEG * Dm;
    const ushort* ETl   = ET + (size_t)dl0 * 32000 + rank * SEG + gst * 8;
    const int l7 = lane & 7, l56 = lane & 56;

    float dacc = 0.f;
    f32x4 acc[2][8] = {};
    const float invT = 0.04419417382415922f;   // 1/sqrt(512)

    for (int ch = 0; ch < CHUNKS; ++ch) {
        const int r0 = split * 800 + ch * CH;
        // stage sE: instr i covers row w*8+i (1 KB, swizzled granules)
        #pragma unroll
        for (int i = 0; i < 8; ++i) {
            int row = w * 8 + i;
            int c = l56 | (l7 ^ (row & 7));
            gll16(EBseg + (size_t)(r0 + row) * Dm + c * 8, sE + row * Dm);
        }
        // stage sET: instr i covers dlocal [ (w*8+i)*16, +16 ) unit-swizzled
        #pragma unroll
        for (int i = 0; i < 8; ++i) {
            int di = w * 8 + i;
            gll16(ETl + (size_t)di * 16 * 32000 + r0, sET + di * 512);
        }
        __syncthreads();   // drain gll16 (vmcnt0 at barrier)

        // ---- QK: S^T[16 rows x 16 slots] per wave, K=512
        f32x4 s4 = {0.f, 0.f, 0.f, 0.f};
        const int arow = rowh * 16 + l15;
        #pragma unroll
        for (int ks = 0; ks < 16; ++ks) {
            int cgr = ks * 4 + quad;
            int p = (cgr & 56) | ((cgr & 7) ^ (arow & 7));
            bf16x8 A = *(const bf16x8*)(sE + arow * Dm + p * 8);
            s4 = __builtin_amdgcn_mfma_f32_16x16x32_bf16(A, Bq[ks], s4, 0, 0, 0);
        }
        float e0 = __expf(s4[0] * invT), e1 = __expf(s4[1] * invT);
        float e2 = __expf(s4[2] * invT), e3 = __expf(s4[3] * invT);
        dacc += e0 + e1 + e2 + e3;
        ushort4 pb; pb.x = f2bf(e0); pb.y = f2bf(e1); pb.z = f2bf(e2); pb.w = f2bf(e3);
        *(ushort4*)(sP + (sloth * 16 + l15) * 36 + rowh * 16 + quad * 4) = pb;
        __syncthreads();   // sP ready; sE reads done

        // ---- PV: O[32 slots][128 d-strip] += P . E
        bf16x8 Ap[2];
        #pragma unroll
        for (int mt = 0; mt < 2; ++mt)
            Ap[mt] = *(const bf16x8*)(sP + (mt * 16 + l15) * 36 + quad * 8);
        #pragma unroll
        for (int nt = 0; nt < 8; ++nt) {
            int d = w * 128 + nt * 16 + l15;
            int u = d >> 1;
            int sp = (quad + ((d & 1) << 2)) ^ (u & 7);
            bf16x8 Bt = *(const bf16x8*)(sET + (u * 8 + sp) * 8);
            #pragma unroll
            for (int mt = 0; mt < 2; ++mt)
                acc[mt][nt] = __builtin_amdgcn_mfma_f32_16x16x32_bf16(Ap[mt], Bt, acc[mt][nt], 0, 0, 0);
        }
        __syncthreads();   // sET/sP reads done before next chunk's staging
    }

    // ---- epilogue: denominators + O atomics (distinct addresses, ~free)
    float s = dacc;
    s += __shfl_xor(s, 16, 64);
    s += __shfl_xor(s, 32, 64);
    if (quad == 0) {
        int tok = perm[slot0 + sloth * 16 + l15];
        if (tok >= 0) atomicAdd(denom + tok, s);
    }
    #pragma unroll
    for (int mt = 0; mt < 2; ++mt) {
        #pragma unroll
        for (int nt = 0; nt < 8; ++nt) {
            const int d = w * 128 + nt * 16 + l15;
            #pragma unroll
            for (int j = 0; j < 4; ++j) {
                const int slot = slot0 + mt * 16 + quad * 4 + j;
                atomicAdd(Oacc + (size_t)slot * Dm + d, acc[mt][nt][j]);
            }
        }
    }
}

// ---- K4: out[tok][d] = Oacc[slot][d]/denom + q ----
__global__ __launch_bounds__(256)
void k_final(const float* __restrict__ q, const int* __restrict__ perm,
             const float* __restrict__ denom, const float* __restrict__ Oacc,
             float* __restrict__ out) {
    const int s = blockIdx.x;
    const int tok = perm[s];
    if (tok < 0) return;
    const float inv = 1.0f / denom[tok];
    const int d = threadIdx.x;
    const float* O = Oacc + (size_t)s * Dm;
    const float* qr = q + (size_t)tok * Dm;
    float* o = out + (size_t)tok * Dm;
    o[d]       = O[d]       * inv + qr[d];
    o[d + 256] = O[d + 256] * inv + qr[d + 256];
}

extern "C" void kernel_launch(void* const* d_in, const int* in_sizes, int n_in,
                              void* d_out, int out_size, void* d_ws, size_t ws_size,
                              hipStream_t stream) {
    const float* q   = (const float*)d_in[0];
    const int*   xr  = (const int*)d_in[1];
    const float* emb = (const float*)d_in[2];
    float* out = (float*)d_out;
    char* ws = (char*)d_ws;

    float*  denom = (float*)(ws + WS_DENOM);
    int*    meta  = (int*)(ws + WS_META);
    int*    perm  = (int*)(ws + WS_PERM);
    ushort* Qb    = (ushort*)(ws + WS_QB);
    float*  Oacc  = (float*)(ws + WS_OACC);
    ushort* EB    = (ushort*)(ws + WS_EB);
    ushort* ET    = (ushort*)(ws + WS_ET);

    k_prep<<<1, 256, 0, stream>>>(xr, meta, perm, denom);
    k_conv<<<dim3(500, 8), 256, 0, stream>>>(emb, EB, ET);
    k_qb<<<MAXSLOTS / 64, 256, 0, stream>>>(q, perm, Qb);
    hipMemsetAsync(Oacc, 0, (size_t)MAXSLOTS * Dm * sizeof(float), stream);
    k_fused<<<RS * MAXT, 256, 0, stream>>>(EB, ET, Qb, meta, perm, denom, Oacc);
    k_final<<<MAXSLOTS, 256, 0, stream>>>(q, perm, denom, Oacc, out);
}

// Round 8
// 233.585 us; speedup vs baseline: 1.2209x; 1.2209x over previous
//
#include <hip/hip_runtime.h>
#include <math.h>

// QueryEmb: B=4,L=512,D=512,V=32000, 4 segments of 8000, TEMP=sqrt(512).
// Equivalences: (1) masked softmax == softmax over token's own segment only;
// (2) |scores|<=~0.35 -> exp() safe without max-subtraction -> plain-sum
//     denoms and trivially split-K PV.
// R8: m97-congruent GEMMs. k_qk: single 32KB buffer, 2-barrier K-loop,
// persistent over 2 row-tiles (16 iters/block, 544 blocks, ~3-4/CU).
// k_pv: same shape, 8 K-splits (544 blocks, 16 iters), bf16 partials
// overlaid on dead EB. k_conv: b128 LDS transpose (no ds_write_b16 scatter).

constexpr int Dm   = 512;
constexpr int SEG  = 8000;
constexpr int NTOK = 2048;
constexpr int TIL  = 128;             // slot tile
constexpr int MAXTILES = 20;          // 2048/128 + 4 pad
constexpr int MAXSLOTS = MAXTILES * TIL;   // 2560

// ws layout (bytes); Oacc (8 bf16 split-K partials, 21 MB) overlays EB
constexpr size_t WS_DENOM = 0;                                  // 2048 f32
constexpr size_t WS_META  = 8192;                               // 8 int
constexpr size_t WS_PERM  = 8448;                               // 2560 int
constexpr size_t WS_QB    = 32768;                              // bf16 [2560][512]
constexpr size_t WS_EB    = 2654208;                            // bf16 [32000][512]
constexpr size_t WS_OACC  = WS_EB;                              // bf16 [8][512][2560] overlay (21<32.8 MB)
constexpr size_t WS_ET    = 35422208;                           // bf16 [512][32000]
constexpr size_t WS_P     = 68190208;                           // bf16 [2560][8000]
// total: 109,150,208 bytes (proven size)

typedef __attribute__((ext_vector_type(8))) short bf16x8;
typedef __attribute__((ext_vector_type(4))) float f32x4;

static __device__ __forceinline__ ushort f2bf(float f) {
    union { float f; unsigned u; } v; v.f = f;
    unsigned r = v.u + 0x7FFF + ((v.u >> 16) & 1);   // RNE
    return (ushort)(r >> 16);
}
static __device__ __forceinline__ float bf2f(ushort u) {
    union { unsigned u; float f; } v; v.u = ((unsigned)u) << 16;
    return v.f;
}

// async global(16B/lane) -> LDS(wave-uniform base + lane*16)
static __device__ __forceinline__ void gll16(const void* g, void* l) {
    __builtin_amdgcn_global_load_lds(
        (const __attribute__((address_space(1))) unsigned int*)g,
        (__attribute__((address_space(3))) unsigned int*)l, 16, 0, 0);
}

// ---- K1: sort tokens by rank into 128-padded slot regions (1 block) ----
__global__ __launch_bounds__(256)
void k_prep(const int* __restrict__ xr, int* __restrict__ meta, int* __restrict__ perm,
            float* __restrict__ denom) {
    __shared__ int cnt[4], base[5], cur[4];
    const int tid = threadIdx.x;
    if (tid < 4) { cnt[tid] = 0; cur[tid] = 0; }
    __syncthreads();
    for (int t = tid; t < NTOK; t += 256) {
        atomicAdd(&cnt[xr[t]], 1);
        denom[t] = 0.f;
    }
    __syncthreads();
    if (tid == 0) {
        base[0] = 0;
        for (int r = 0; r < 4; ++r) base[r+1] = base[r] + ((cnt[r] + TIL - 1) / TIL) * TIL;
        for (int r = 0; r < 5; ++r) meta[r] = base[r];
    }
    __syncthreads();
    for (int s = tid; s < MAXSLOTS; s += 256) perm[s] = -1;
    __syncthreads();
    for (int t = tid; t < NTOK; t += 256) {
        int r = xr[t];
        perm[base[r] + atomicAdd(&cur[r], 1)] = t;
    }
}

// ---- K2: emb fp32 -> EB bf16 row-major + ET bf16 transposed, b128 LDS ops ----
// Tile 128 rows x 64 d. sT granule (d, g): 8 rows of one d, at (d*16 + (g^(d&15)))*16B.
__global__ __launch_bounds__(256)
void k_conv(const float* __restrict__ emb, ushort* __restrict__ EB, ushort* __restrict__ ET) {
    __shared__ ushort sT[64 * 128];   // 16 KB
    const int tid = threadIdx.x;
    const int r0 = blockIdx.x * 128, d0 = blockIdx.y * 64;
    {
        const int dq = tid & 15, ro = tid >> 4;     // d-quad (4 d's), row-oct (8 rows)
        ushort4 u[8];
        #pragma unroll
        for (int i = 0; i < 8; ++i) {
            float4 v = *(const float4*)(emb + (size_t)(r0 + ro*8 + i) * Dm + d0 + dq*4);
            u[i].x = f2bf(v.x); u[i].y = f2bf(v.y); u[i].z = f2bf(v.z); u[i].w = f2bf(v.w);
            *(ushort4*)(EB + (size_t)(r0 + ro*8 + i) * Dm + d0 + dq*4) = u[i];
        }
        #pragma unroll
        for (int j = 0; j < 4; ++j) {               // pack 8 rows of d = dq*4+j
            const int d = dq*4 + j;
            ushort tmp[8];
            #pragma unroll
            for (int i = 0; i < 8; ++i)
                tmp[i] = (j==0) ? u[i].x : (j==1) ? u[i].y : (j==2) ? u[i].z : u[i].w;
            *(uint4*)(sT + (d*16 + (ro ^ (d & 15))) * 8) = *(const uint4*)tmp;
        }
    }
    __syncthreads();
    {
        const int d = tid >> 2, rq = tid & 3;
        ushort* dst = ET + (size_t)(d0 + d) * 32000 + r0;
        #pragma unroll
        for (int i = 0; i < 4; ++i) {
            const int g = i*4 + rq;                 // rq inner: 4x16B contiguous per d
            *(uint4*)(dst + g*8) = *(const uint4*)(sT + (d*16 + (g ^ (d & 15))) * 8);
        }
    }
}

// ---- K2b: gather Q -> Qb bf16 [2560 slots][512] (pad slots zeroed) ----
__global__ __launch_bounds__(256)
void k_qb(const float* __restrict__ q, const int* __restrict__ perm, ushort* __restrict__ Qb) {
    const int slot = blockIdx.x * 8 + (threadIdx.x >> 5);
    const int ln = threadIdx.x & 31;
    const int tok = perm[slot];
    #pragma unroll
    for (int j = 0; j < 4; ++j) {
        const int c4 = ln + j * 32;
        ushort4 u;
        if (tok >= 0) {
            float4 v = ((const float4*)q)[(size_t)tok * 128 + c4];
            u.x=f2bf(v.x); u.y=f2bf(v.y); u.z=f2bf(v.z); u.w=f2bf(v.w);
        } else { u.x = u.y = u.z = u.w = 0; }
        ((ushort4*)(Qb + (size_t)slot * Dm))[c4] = u;
    }
}

// ---- K3: S^T = E.Q^T; persistent over 2 row-tiles; single-buf 2-barrier loop ----
__global__ __launch_bounds__(256)
void k_qk(const ushort* __restrict__ EB, const ushort* __restrict__ Qb,
          const int* __restrict__ meta, const int* __restrict__ perm,
          float* __restrict__ denom, ushort* __restrict__ P) {
    __shared__ ushort sA[128 * 64];   // 16 KB, swizzled granules
    __shared__ ushort sB[128 * 64];
    const int tid = threadIdx.x, lane = tid & 63, w = tid >> 6;
    const int cg = blockIdx.x / MAXTILES;     // row-tile pair 0..31 (c = cg*2, cg*2+1)
    const int tt = blockIdx.x % MAXTILES;
    const int slot0 = tt * TIL;
    const int b1 = meta[1], b2 = meta[2], b3 = meta[3], b4 = meta[4];
    if (slot0 >= b4) return;
    const int rank = (slot0 >= b1) + (slot0 >= b2) + (slot0 >= b3);

    int preA[2][4], preB[4];
    #pragma unroll
    for (int i = 0; i < 4; ++i) {
        const int g = w * 256 + i * 64 + lane;
        const int r = g >> 3, cc = g & 7, cs = cc ^ (r & 7);
        #pragma unroll
        for (int cl = 0; cl < 2; ++cl) {
            int grow = cg * 256 + cl * 128 + r;
            if (grow >= SEG) grow = SEG - 1;        // tail clamp (masked in epilogue)
            preA[cl][i] = grow * Dm + cs * 8;
        }
        preB[i] = (slot0 + r) * Dm + cs * 8;
    }
    const ushort* EBseg = EB + (size_t)rank * SEG * Dm;
    const int rh = w >> 1, th = w & 1, quad = lane >> 4, l15 = lane & 15;
    const float invT = 0.04419417382415922f;   // 1/sqrt(512)

    f32x4 acc[4][4] = {};
    float dsum[4] = {0.f, 0.f, 0.f, 0.f};

    #pragma unroll
    for (int it = 0; it < 16; ++it) {          // 2 row-tiles x 8 K-iters
        const int cl = it >> 3, k0 = (it & 7) << 6;
        #pragma unroll
        for (int i = 0; i < 4; ++i) {
            gll16(EBseg + preA[cl][i] + k0, (char*)sA + (w * 256 + i * 64) * 16);
            gll16(Qb    + preB[i]     + k0, (char*)sB + (w * 256 + i * 64) * 16);
        }
        __syncthreads();                       // drain staging
        #pragma unroll
        for (int ks = 0; ks < 2; ++ks) {
            bf16x8 A[4], B[4];
            #pragma unroll
            for (int m = 0; m < 4; ++m)
                A[m] = *(const bf16x8*)(sA + ((rh*64 + m*16 + l15)*8 + ((ks*4+quad) ^ (l15&7)))*8);
            #pragma unroll
            for (int n = 0; n < 4; ++n)
                B[n] = *(const bf16x8*)(sB + ((th*64 + n*16 + l15)*8 + ((ks*4+quad) ^ (l15&7)))*8);
            #pragma unroll
            for (int m = 0; m < 4; ++m)
                #pragma unroll
                for (int n = 0; n < 4; ++n)
                    acc[m][n] = __builtin_amdgcn_mfma_f32_16x16x32_bf16(A[m], B[n], acc[m][n], 0, 0, 0);
        }
        __syncthreads();                       // compute done before next overwrite
        if ((it & 7) == 7) {
            // epilogue for row-tile c = cg*2+cl (reads acc regs only; safe past barrier)
            const int row0 = cg * 256 + cl * 128;
            #pragma unroll
            for (int m = 0; m < 4; ++m) {
                const int r4 = row0 + rh*64 + m*16 + quad*4;
                if (r4 < SEG) {                // 8000%4==0: all-or-none
                    #pragma unroll
                    for (int n = 0; n < 4; ++n) {
                        float e0 = __expf(acc[m][n][0] * invT);
                        float e1 = __expf(acc[m][n][1] * invT);
                        float e2 = __expf(acc[m][n][2] * invT);
                        float e3 = __expf(acc[m][n][3] * invT);
                        ushort4 pb; pb.x=f2bf(e0); pb.y=f2bf(e1); pb.z=f2bf(e2); pb.w=f2bf(e3);
                        const int slot = slot0 + th*64 + n*16 + l15;
                        *(ushort4*)(P + (size_t)slot * SEG + r4) = pb;
                        dsum[n] += e0 + e1 + e2 + e3;
                    }
                }
            }
            #pragma unroll
            for (int m = 0; m < 4; ++m)
                #pragma unroll
                for (int n = 0; n < 4; ++n)
                    acc[m][n] = (f32x4){0.f, 0.f, 0.f, 0.f};
        }
    }

    #pragma unroll
    for (int n = 0; n < 4; ++n) {
        float s = dsum[n];
        s += __shfl_xor(s, 16, 64);
        s += __shfl_xor(s, 32, 64);
        if (quad == 0) {
            const int tok = perm[slot0 + th*64 + n*16 + l15];
            if (tok >= 0) atomicAdd(denom + tok, s);
        }
    }
}

// ---- K4: O^T = E^T.P^T, 8 K-splits of 1024 rows, single-buf, bf16 partials ----
__global__ __launch_bounds__(256)
void k_pv(const ushort* __restrict__ ET, const ushort* __restrict__ P,
          const int* __restrict__ meta, ushort* __restrict__ Oacc) {
    __shared__ ushort sA[128 * 64];
    __shared__ ushort sB[128 * 64];
    const int tid = threadIdx.x, lane = tid & 63, w = tid >> 6;
    const int z   = blockIdx.x / (4 * MAXTILES);      // 0..7 (K-split)
    const int rem = blockIdx.x % (4 * MAXTILES);
    const int dt  = rem / MAXTILES;                   // d-tile 0..3
    const int tt  = rem % MAXTILES;
    const int slot0 = tt * TIL;
    const int b1 = meta[1], b2 = meta[2], b3 = meta[3], b4 = meta[4];
    if (slot0 >= b4) return;
    const int rank = (slot0 >= b1) + (slot0 >= b2) + (slot0 >= b3);
    const int d0 = dt * 128;
    const int kstart = z * 1024;
    const int nit = ((z == 7 ? SEG : kstart + 1024) - kstart) >> 6;   // 16 or 13

    int preA[4], preB[4];
    #pragma unroll
    for (int i = 0; i < 4; ++i) {
        const int g = w * 256 + i * 64 + lane;
        const int r = g >> 3, cc = g & 7, cs = cc ^ (r & 7);
        preA[i] = (d0 + r) * 32000 + cs * 8;
        preB[i] = (slot0 + r) * SEG + cs * 8;
    }
    const ushort* ETseg = ET + (size_t)rank * SEG;
    const int rh = w >> 1, th = w & 1, quad = lane >> 4, l15 = lane & 15;

    f32x4 acc[4][4] = {};
    for (int it = 0; it < nit; ++it) {
        const int k0 = kstart + (it << 6);
        #pragma unroll
        for (int i = 0; i < 4; ++i) {
            gll16(ETseg + preA[i] + k0, (char*)sA + (w * 256 + i * 64) * 16);
            gll16(P     + preB[i] + k0, (char*)sB + (w * 256 + i * 64) * 16);
        }
        __syncthreads();
        #pragma unroll
        for (int ks = 0; ks < 2; ++ks) {
            bf16x8 A[4], B[4];
            #pragma unroll
            for (int m = 0; m < 4; ++m)
                A[m] = *(const bf16x8*)(sA + ((rh*64 + m*16 + l15)*8 + ((ks*4+quad) ^ (l15&7)))*8);
            #pragma unroll
            for (int n = 0; n < 4; ++n)
                B[n] = *(const bf16x8*)(sB + ((th*64 + n*16 + l15)*8 + ((ks*4+quad) ^ (l15&7)))*8);
            #pragma unroll
            for (int m = 0; m < 4; ++m)
                #pragma unroll
                for (int n = 0; n < 4; ++n)
                    acc[m][n] = __builtin_amdgcn_mfma_f32_16x16x32_bf16(A[m], B[n], acc[m][n], 0, 0, 0);
        }
        __syncthreads();
    }
    ushort* Oz = Oacc + (size_t)z * Dm * MAXSLOTS;
    #pragma unroll
    for (int m = 0; m < 4; ++m) {
        const int d4 = d0 + rh*64 + m*16 + quad*4;
        #pragma unroll
        for (int n = 0; n < 4; ++n) {
            const int slot = slot0 + th*64 + n*16 + l15;
            #pragma unroll
            for (int j = 0; j < 4; ++j)
                Oz[(size_t)(d4 + j) * MAXSLOTS + slot] = f2bf(acc[m][n][j]);
        }
    }
}

// ---- K5: out[tok][d] = (sum_z Oacc[z][d][slot]) / denom + q ----
__global__ __launch_bounds__(256)
void k_final(const float* __restrict__ q, const int* __restrict__ meta,
             const int* __restrict__ perm, const float* __restrict__ denom,
             const ushort* __restrict__ Oacc, float* __restrict__ out) {
    const int d = blockIdx.x;
    const int ns = meta[4];
    for (int s = threadIdx.x; s < ns; s += 256) {
        const int tok = perm[s];
        if (tok < 0) continue;
        float v = 0.f;
        #pragma unroll
        for (int z = 0; z < 8; ++z)
            v += bf2f(Oacc[((size_t)z * Dm + d) * MAXSLOTS + s]);
        out[(size_t)tok * Dm + d] = v / denom[tok] + q[(size_t)tok * Dm + d];
    }
}

extern "C" void kernel_launch(void* const* d_in, const int* in_sizes, int n_in,
                              void* d_out, int out_size, void* d_ws, size_t ws_size,
                              hipStream_t stream) {
    const float* q   = (const float*)d_in[0];
    const int*   xr  = (const int*)d_in[1];
    const float* emb = (const float*)d_in[2];
    float* out = (float*)d_out;
    char* ws = (char*)d_ws;

    float*  denom = (float*)(ws + WS_DENOM);
    int*    meta  = (int*)(ws + WS_META);
    int*    perm  = (int*)(ws + WS_PERM);
    ushort* Qb    = (ushort*)(ws + WS_QB);
    ushort* EB    = (ushort*)(ws + WS_EB);
    ushort* Oacc  = (ushort*)(ws + WS_OACC);   // overlays EB (dead after k_qk)
    ushort* ET    = (ushort*)(ws + WS_ET);
    ushort* P     = (ushort*)(ws + WS_P);

    k_prep<<<1, 256, 0, stream>>>(xr, meta, perm, denom);
    k_conv<<<dim3(250, 8), 256, 0, stream>>>(emb, EB, ET);
    k_qb<<<MAXSLOTS / 8, 256, 0, stream>>>(q, perm, Qb);
    k_qk<<<32 * MAXTILES, 256, 0, stream>>>(EB, Qb, meta, perm, denom, P);
    k_pv<<<8 * 4 * MAXTILES, 256, 0, stream>>>(ET, P, meta, Oacc);
    k_final<<<Dm, 256, 0, stream>>>(q, meta, perm, denom, Oacc, out);
}

// Round 9
// 210.556 us; speedup vs baseline: 1.3545x; 1.1094x over previous
//
#include <hip/hip_runtime.h>
#include <math.h>

// QueryEmb: B=4,L=512,D=512,V=32000, 4 segments of 8000, TEMP=sqrt(512).
// Equivalences: (1) masked softmax == softmax over token's own segment only;
// (2) |scores|<=~0.35 -> exp() safe without max-subtraction -> plain-sum
//     denoms and trivially split-K PV.
// R9: occupancy x locality. k_qk: 1280 blocks (4-5/CU co-resident; R6/R8 both
// accidentally capped at 2), 32KB single buffer, __launch_bounds__(256,4).
// XCD binding via bid&7: XCD g owns row-tiles [8g,8g+8) (k_qk) / K-split z=g
// (k_pv), tt-inner -> per-XCD EB/ET working set ~3-5 MB stays L2-resident.

constexpr int Dm   = 512;
constexpr int SEG  = 8000;
constexpr int NTOK = 2048;
constexpr int TIL  = 128;             // slot tile
constexpr int MAXTILES = 20;          // 2048/128 + 4 pad
constexpr int MAXSLOTS = MAXTILES * TIL;   // 2560

// ws layout (bytes); Oacc (8 bf16 split-K partials, 21 MB) overlays EB
constexpr size_t WS_DENOM = 0;                                  // 2048 f32
constexpr size_t WS_META  = 8192;                               // 8 int
constexpr size_t WS_PERM  = 8448;                               // 2560 int
constexpr size_t WS_QB    = 32768;                              // bf16 [2560][512]
constexpr size_t WS_EB    = 2654208;                            // bf16 [32000][512]
constexpr size_t WS_OACC  = WS_EB;                              // bf16 [8][512][2560] overlay (21<32.8 MB)
constexpr size_t WS_ET    = 35422208;                           // bf16 [512][32000]
constexpr size_t WS_P     = 68190208;                           // bf16 [2560][8000]
// total: 109,150,208 bytes (proven size)

typedef __attribute__((ext_vector_type(8))) short bf16x8;
typedef __attribute__((ext_vector_type(4))) float f32x4;

static __device__ __forceinline__ ushort f2bf(float f) {
    union { float f; unsigned u; } v; v.f = f;
    unsigned r = v.u + 0x7FFF + ((v.u >> 16) & 1);   // RNE
    return (ushort)(r >> 16);
}
static __device__ __forceinline__ float bf2f(ushort u) {
    union { unsigned u; float f; } v; v.u = ((unsigned)u) << 16;
    return v.f;
}

// async global(16B/lane) -> LDS(wave-uniform base + lane*16)
static __device__ __forceinline__ void gll16(const void* g, void* l) {
    __builtin_amdgcn_global_load_lds(
        (const __attribute__((address_space(1))) unsigned int*)g,
        (__attribute__((address_space(3))) unsigned int*)l, 16, 0, 0);
}

// ---- K1: sort tokens by rank into 128-padded slot regions (1 block) ----
__global__ __launch_bounds__(256)
void k_prep(const int* __restrict__ xr, int* __restrict__ meta, int* __restrict__ perm,
            float* __restrict__ denom) {
    __shared__ int cnt[4], base[5], cur[4];
    const int tid = threadIdx.x;
    if (tid < 4) { cnt[tid] = 0; cur[tid] = 0; }
    __syncthreads();
    for (int t = tid; t < NTOK; t += 256) {
        atomicAdd(&cnt[xr[t]], 1);
        denom[t] = 0.f;
    }
    __syncthreads();
    if (tid == 0) {
        base[0] = 0;
        for (int r = 0; r < 4; ++r) base[r+1] = base[r] + ((cnt[r] + TIL - 1) / TIL) * TIL;
        for (int r = 0; r < 5; ++r) meta[r] = base[r];
    }
    __syncthreads();
    for (int s = tid; s < MAXSLOTS; s += 256) perm[s] = -1;
    __syncthreads();
    for (int t = tid; t < NTOK; t += 256) {
        int r = xr[t];
        perm[base[r] + atomicAdd(&cur[r], 1)] = t;
    }
}

// ---- K2: emb fp32 -> EB bf16 row-major + ET bf16 transposed, b128 LDS ops ----
__global__ __launch_bounds__(256)
void k_conv(const float* __restrict__ emb, ushort* __restrict__ EB, ushort* __restrict__ ET) {
    __shared__ ushort sT[64 * 128];   // 16 KB
    const int tid = threadIdx.x;
    const int r0 = blockIdx.x * 128, d0 = blockIdx.y * 64;
    {
        const int dq = tid & 15, ro = tid >> 4;     // d-quad (4 d's), row-oct (8 rows)
        ushort4 u[8];
        #pragma unroll
        for (int i = 0; i < 8; ++i) {
            float4 v = *(const float4*)(emb + (size_t)(r0 + ro*8 + i) * Dm + d0 + dq*4);
            u[i].x = f2bf(v.x); u[i].y = f2bf(v.y); u[i].z = f2bf(v.z); u[i].w = f2bf(v.w);
            *(ushort4*)(EB + (size_t)(r0 + ro*8 + i) * Dm + d0 + dq*4) = u[i];
        }
        #pragma unroll
        for (int j = 0; j < 4; ++j) {               // pack 8 rows of d = dq*4+j
            const int d = dq*4 + j;
            ushort tmp[8];
            #pragma unroll
            for (int i = 0; i < 8; ++i)
                tmp[i] = (j==0) ? u[i].x : (j==1) ? u[i].y : (j==2) ? u[i].z : u[i].w;
            *(uint4*)(sT + (d*16 + (ro ^ (d & 15))) * 8) = *(const uint4*)tmp;
        }
    }
    __syncthreads();
    {
        const int d = tid >> 2, rq = tid & 3;
        ushort* dst = ET + (size_t)(d0 + d) * 32000 + r0;
        #pragma unroll
        for (int i = 0; i < 4; ++i) {
            const int g = i*4 + rq;                 // rq inner: 4x16B contiguous per d
            *(uint4*)(dst + g*8) = *(const uint4*)(sT + (d*16 + (g ^ (d & 15))) * 8);
        }
    }
}

// ---- K2b: gather Q -> Qb bf16 [2560 slots][512] (pad slots zeroed) ----
__global__ __launch_bounds__(256)
void k_qb(const float* __restrict__ q, const int* __restrict__ perm, ushort* __restrict__ Qb) {
    const int slot = blockIdx.x * 8 + (threadIdx.x >> 5);
    const int ln = threadIdx.x & 31;
    const int tok = perm[slot];
    #pragma unroll
    for (int j = 0; j < 4; ++j) {
        const int c4 = ln + j * 32;
        ushort4 u;
        if (tok >= 0) {
            float4 v = ((const float4*)q)[(size_t)tok * 128 + c4];
            u.x=f2bf(v.x); u.y=f2bf(v.y); u.z=f2bf(v.z); u.w=f2bf(v.w);
        } else { u.x = u.y = u.z = u.w = 0; }
        ((ushort4*)(Qb + (size_t)slot * Dm))[c4] = u;
    }
}

// ---- K3: S^T = E.Q^T; 32KB single-buf; XCD-bound row-tiles; 4+ blocks/CU ----
__global__ __launch_bounds__(256, 4)
void k_qk(const ushort* __restrict__ EB, const ushort* __restrict__ Qb,
          const int* __restrict__ meta, const int* __restrict__ perm,
          float* __restrict__ denom, ushort* __restrict__ P) {
    __shared__ ushort sA[128 * 64];   // 16 KB, swizzled granules
    __shared__ ushort sB[128 * 64];
    const int tid = threadIdx.x, lane = tid & 63, w = tid >> 6;
    const int g    = blockIdx.x & 7;              // XCD group
    const int rest = blockIdx.x >> 3;             // 0..159
    const int rt_local = rest / MAXTILES;         // 0..7 (row-tile within XCD)
    const int tt       = rest % MAXTILES;         // slot tile (inner)
    const int c = g * 8 + rt_local;               // row-tile 0..63 (tile 63 fully clamped)
    const int slot0 = tt * TIL;
    const int b1 = meta[1], b2 = meta[2], b3 = meta[3], b4 = meta[4];
    if (slot0 >= b4) return;
    const int rank = (slot0 >= b1) + (slot0 >= b2) + (slot0 >= b3);
    const int row0 = c * 128;

    int preA[4], preB[4];
    #pragma unroll
    for (int i = 0; i < 4; ++i) {
        const int gg = w * 256 + i * 64 + lane;
        const int r = gg >> 3, cc = gg & 7, cs = cc ^ (r & 7);
        int grow = row0 + r;
        if (grow >= SEG) grow = SEG - 1;          // tail clamp (masked in epilogue)
        preA[i] = grow * Dm + cs * 8;
        preB[i] = (slot0 + r) * Dm + cs * 8;
    }
    const ushort* EBseg = EB + (size_t)rank * SEG * Dm;
    const int rh = w >> 1, th = w & 1, quad = lane >> 4, l15 = lane & 15;
    const float invT = 0.04419417382415922f;   // 1/sqrt(512)

    f32x4 acc[4][4] = {};
    #pragma unroll
    for (int it = 0; it < 8; ++it) {           // K = 512, BK = 64
        const int k0 = it << 6;
        #pragma unroll
        for (int i = 0; i < 4; ++i) {
            gll16(EBseg + preA[i] + k0, (char*)sA + (w * 256 + i * 64) * 16);
            gll16(Qb    + preB[i] + k0, (char*)sB + (w * 256 + i * 64) * 16);
        }
        __syncthreads();                       // drain staging
        #pragma unroll
        for (int ks = 0; ks < 2; ++ks) {
            bf16x8 A[4], B[4];
            #pragma unroll
            for (int m = 0; m < 4; ++m)
                A[m] = *(const bf16x8*)(sA + ((rh*64 + m*16 + l15)*8 + ((ks*4+quad) ^ (l15&7)))*8);
            #pragma unroll
            for (int n = 0; n < 4; ++n)
                B[n] = *(const bf16x8*)(sB + ((th*64 + n*16 + l15)*8 + ((ks*4+quad) ^ (l15&7)))*8);
            #pragma unroll
            for (int m = 0; m < 4; ++m)
                #pragma unroll
                for (int n = 0; n < 4; ++n)
                    acc[m][n] = __builtin_amdgcn_mfma_f32_16x16x32_bf16(A[m], B[n], acc[m][n], 0, 0, 0);
        }
        __syncthreads();                       // compute done before next overwrite
    }

    float dsum[4] = {0.f, 0.f, 0.f, 0.f};
    #pragma unroll
    for (int m = 0; m < 4; ++m) {
        const int r4 = row0 + rh*64 + m*16 + quad*4;
        if (r4 < SEG) {                        // 8000%4==0: all-or-none per quad
            #pragma unroll
            for (int n = 0; n < 4; ++n) {
                float e0 = __expf(acc[m][n][0] * invT);
                float e1 = __expf(acc[m][n][1] * invT);
                float e2 = __expf(acc[m][n][2] * invT);
                float e3 = __expf(acc[m][n][3] * invT);
                ushort4 pb; pb.x=f2bf(e0); pb.y=f2bf(e1); pb.z=f2bf(e2); pb.w=f2bf(e3);
                const int slot = slot0 + th*64 + n*16 + l15;
                *(ushort4*)(P + (size_t)slot * SEG + r4) = pb;
                dsum[n] += e0 + e1 + e2 + e3;
            }
        }
    }
    #pragma unroll
    for (int n = 0; n < 4; ++n) {
        float s = dsum[n];
        s += __shfl_xor(s, 16, 64);
        s += __shfl_xor(s, 32, 64);
        if (quad == 0) {
            const int tok = perm[slot0 + th*64 + n*16 + l15];
            if (tok >= 0) atomicAdd(denom + tok, s);
        }
    }
}

// ---- K4: O^T = E^T.P^T; K-split z bound to XCD (z = bid&7); bf16 partials ----
__global__ __launch_bounds__(256, 4)
void k_pv(const ushort* __restrict__ ET, const ushort* __restrict__ P,
          const int* __restrict__ meta, ushort* __restrict__ Oacc) {
    __shared__ ushort sA[128 * 64];
    __shared__ ushort sB[128 * 64];
    const int tid = threadIdx.x, lane = tid & 63, w = tid >> 6;
    const int z    = blockIdx.x & 7;              // K-split == XCD group
    const int rest = blockIdx.x >> 3;             // 0..79
    const int dt   = rest / MAXTILES;             // d-tile 0..3 (outer)
    const int tt   = rest % MAXTILES;             // slot tile (inner)
    const int slot0 = tt * TIL;
    const int b1 = meta[1], b2 = meta[2], b3 = meta[3], b4 = meta[4];
    if (slot0 >= b4) return;
    const int rank = (slot0 >= b1) + (slot0 >= b2) + (slot0 >= b3);
    const int d0 = dt * 128;
    const int kstart = z * 1024;
    const int nit = ((z == 7 ? SEG : kstart + 1024) - kstart) >> 6;   // 16 or 13

    int preA[4], preB[4];
    #pragma unroll
    for (int i = 0; i < 4; ++i) {
        const int gg = w * 256 + i * 64 + lane;
        const int r = gg >> 3, cc = gg & 7, cs = cc ^ (r & 7);
        preA[i] = (d0 + r) * 32000 + cs * 8;
        preB[i] = (slot0 + r) * SEG + cs * 8;
    }
    const ushort* ETseg = ET + (size_t)rank * SEG;
    const int rh = w >> 1, th = w & 1, quad = lane >> 4, l15 = lane & 15;

    f32x4 acc[4][4] = {};
    for (int it = 0; it < nit; ++it) {
        const int k0 = kstart + (it << 6);
        #pragma unroll
        for (int i = 0; i < 4; ++i) {
            gll16(ETseg + preA[i] + k0, (char*)sA + (w * 256 + i * 64) * 16);
            gll16(P     + preB[i] + k0, (char*)sB + (w * 256 + i * 64) * 16);
        }
        __syncthreads();
        #pragma unroll
        for (int ks = 0; ks < 2; ++ks) {
            bf16x8 A[4], B[4];
            #pragma unroll
            for (int m = 0; m < 4; ++m)
                A[m] = *(const bf16x8*)(sA + ((rh*64 + m*16 + l15)*8 + ((ks*4+quad) ^ (l15&7)))*8);
            #pragma unroll
            for (int n = 0; n < 4; ++n)
                B[n] = *(const bf16x8*)(sB + ((th*64 + n*16 + l15)*8 + ((ks*4+quad) ^ (l15&7)))*8);
            #pragma unroll
            for (int m = 0; m < 4; ++m)
                #pragma unroll
                for (int n = 0; n < 4; ++n)
                    acc[m][n] = __builtin_amdgcn_mfma_f32_16x16x32_bf16(A[m], B[n], acc[m][n], 0, 0, 0);
        }
        __syncthreads();
    }
    ushort* Oz = Oacc + (size_t)z * Dm * MAXSLOTS;
    #pragma unroll
    for (int m = 0; m < 4; ++m) {
        const int d4 = d0 + rh*64 + m*16 + quad*4;
        #pragma unroll
        for (int n = 0; n < 4; ++n) {
            const int slot = slot0 + th*64 + n*16 + l15;
            #pragma unroll
            for (int j = 0; j < 4; ++j)
                Oz[(size_t)(d4 + j) * MAXSLOTS + slot] = f2bf(acc[m][n][j]);
        }
    }
}

// ---- K5: out[tok][d] = (sum_z Oacc[z][d][slot]) / denom + q ----
__global__ __launch_bounds__(256)
void k_final(const float* __restrict__ q, const int* __restrict__ meta,
             const int* __restrict__ perm, const float* __restrict__ denom,
             const ushort* __restrict__ Oacc, float* __restrict__ out) {
    const int d = blockIdx.x;
    const int ns = meta[4];
    for (int s = threadIdx.x; s < ns; s += 256) {
        const int tok = perm[s];
        if (tok < 0) continue;
        float v = 0.f;
        #pragma unroll
        for (int z = 0; z < 8; ++z)
            v += bf2f(Oacc[((size_t)z * Dm + d) * MAXSLOTS + s]);
        out[(size_t)tok * Dm + d] = v / denom[tok] + q[(size_t)tok * Dm + d];
    }
}

extern "C" void kernel_launch(void* const* d_in, const int* in_sizes, int n_in,
                              void* d_out, int out_size, void* d_ws, size_t ws_size,
                              hipStream_t stream) {
    const float* q   = (const float*)d_in[0];
    const int*   xr  = (const int*)d_in[1];
    const float* emb = (const float*)d_in[2];
    float* out = (float*)d_out;
    char* ws = (char*)d_ws;

    float*  denom = (float*)(ws + WS_DENOM);
    int*    meta  = (int*)(ws + WS_META);
    int*    perm  = (int*)(ws + WS_PERM);
    ushort* Qb    = (ushort*)(ws + WS_QB);
    ushort* EB    = (ushort*)(ws + WS_EB);
    ushort* Oacc  = (ushort*)(ws + WS_OACC);   // overlays EB (dead after k_qk)
    ushort* ET    = (ushort*)(ws + WS_ET);
    ushort* P     = (ushort*)(ws + WS_P);

    k_prep<<<1, 256, 0, stream>>>(xr, meta, perm, denom);
    k_conv<<<dim3(250, 8), 256, 0, stream>>>(emb, EB, ET);
    k_qb<<<MAXSLOTS / 8, 256, 0, stream>>>(q, perm, Qb);
    k_qk<<<8 * 8 * MAXTILES, 256, 0, stream>>>(EB, Qb, meta, perm, denom, P);
    k_pv<<<8 * 4 * MAXTILES, 256, 0, stream>>>(ET, P, meta, Oacc);
    k_final<<<Dm, 256, 0, stream>>>(q, meta, perm, denom, Oacc, out);
}

// Round 10
// 193.363 us; speedup vs baseline: 1.4749x; 1.0889x over previous
//
#include <hip/hip_runtime.h>
#include <math.h>

// QueryEmb: B=4,L=512,D=512,V=32000, 4 segments of 8000, TEMP=sqrt(512).
// Equivalences: (1) masked softmax == softmax over token's own segment only;
// (2) |scores|<=~0.35 -> exp() safe without max-subtraction -> plain-sum
//     denoms and trivially split-K PV.
// R10: full fp8-e4m3 port. All staged operands (EB, ET, Qb, P) stored fp8 ->
// staged bytes halve, BK=128 at the same 32KB LDS/iter -> half the barriers,
// 2x MFMA per barrier. P stride 8064 (63x128) with zero-filled pad rows
// 8000..8063 so k_pv's BK=128 tail multiplies by zero. R9's XCD binding and
// occupancy setup kept (FETCH was already minimal at 34 MB).

constexpr int Dm   = 512;
constexpr int SEG  = 8000;
constexpr int PSTR = 8064;            // P row stride (63*128), pad rows zeroed
constexpr int NTOK = 2048;
constexpr int TIL  = 128;             // slot tile
constexpr int MAXTILES = 20;          // 2048/128 + 4 pad
constexpr int MAXSLOTS = MAXTILES * TIL;   // 2560

// ws layout (bytes)
constexpr size_t WS_DENOM = 0;                                   // 2048 f32
constexpr size_t WS_META  = 8192;                                // 8 int
constexpr size_t WS_PERM  = 8448;                                // 2560 int
constexpr size_t WS_QB8   = 32768;                               // fp8 [2560][512]
constexpr size_t WS_EB8   = WS_QB8 + (size_t)MAXSLOTS * Dm;      // fp8 [32000][512]
constexpr size_t WS_OACC  = WS_EB8 + (size_t)32000 * Dm;         // bf16 [8][512][2560]
constexpr size_t WS_ET8   = WS_OACC + (size_t)8 * Dm * MAXSLOTS * 2;  // fp8 [512][32000]
constexpr size_t WS_P8    = WS_ET8 + (size_t)Dm * 32000;         // fp8 [2560][8064]
// total ~75.7 MB (< proven 104 MB)

typedef __attribute__((ext_vector_type(4))) float f32x4;

static __device__ __forceinline__ ushort f2bf(float f) {
    union { float f; unsigned u; } v; v.f = f;
    unsigned r = v.u + 0x7FFF + ((v.u >> 16) & 1);   // RNE
    return (ushort)(r >> 16);
}
static __device__ __forceinline__ float bf2f(ushort u) {
    union { unsigned u; float f; } v; v.u = ((unsigned)u) << 16;
    return v.f;
}
// pack 4 floats -> 4 OCP fp8 e4m3 bytes (byte0 = a .. byte3 = d)
static __device__ __forceinline__ int pack_fp8x4(float a, float b, float c, float d) {
    int r = __builtin_amdgcn_cvt_pk_fp8_f32(a, b, 0, false);
    r = __builtin_amdgcn_cvt_pk_fp8_f32(c, d, r, true);
    return r;
}

// async global(16B/lane) -> LDS(wave-uniform base + lane*16)
static __device__ __forceinline__ void gll16(const void* g, void* l) {
    __builtin_amdgcn_global_load_lds(
        (const __attribute__((address_space(1))) unsigned int*)g,
        (__attribute__((address_space(3))) unsigned int*)l, 16, 0, 0);
}

// ---- K1: sort tokens by rank into 128-padded slot regions (1 block) ----
__global__ __launch_bounds__(256)
void k_prep(const int* __restrict__ xr, int* __restrict__ meta, int* __restrict__ perm,
            float* __restrict__ denom) {
    __shared__ int cnt[4], base[5], cur[4];
    const int tid = threadIdx.x;
    if (tid < 4) { cnt[tid] = 0; cur[tid] = 0; }
    __syncthreads();
    for (int t = tid; t < NTOK; t += 256) {
        atomicAdd(&cnt[xr[t]], 1);
        denom[t] = 0.f;
    }
    __syncthreads();
    if (tid == 0) {
        base[0] = 0;
        for (int r = 0; r < 4; ++r) base[r+1] = base[r] + ((cnt[r] + TIL - 1) / TIL) * TIL;
        for (int r = 0; r < 5; ++r) meta[r] = base[r];
    }
    __syncthreads();
    for (int s = tid; s < MAXSLOTS; s += 256) perm[s] = -1;
    __syncthreads();
    for (int t = tid; t < NTOK; t += 256) {
        int r = xr[t];
        perm[base[r] + atomicAdd(&cur[r], 1)] = t;
    }
}

// ---- K2: emb fp32 -> EB8 fp8 row-major + ET8 fp8 transposed ----
// Tile 128 rows x 64 d. sT granule (d, gr): 16 rows of one d (16 B) at
// (d*8 + (gr ^ (d&7)))*16; write half-granules (8 rows, b64) per thread.
__global__ __launch_bounds__(256)
void k_conv(const float* __restrict__ emb, unsigned char* __restrict__ EB8,
            unsigned char* __restrict__ ET8) {
    __shared__ unsigned char sT[64 * 8 * 16];   // 8 KB
    const int tid = threadIdx.x;
    const int r0 = blockIdx.x * 128, d0 = blockIdx.y * 64;
    {
        const int dq = tid & 15, ro = tid >> 4;     // 4-d group, 8-row group
        int p[8];
        #pragma unroll
        for (int i = 0; i < 8; ++i) {
            float4 v = *(const float4*)(emb + (size_t)(r0 + ro*8 + i) * Dm + d0 + dq*4);
            p[i] = pack_fp8x4(v.x, v.y, v.z, v.w);
            *(int*)(EB8 + (size_t)(r0 + ro*8 + i) * Dm + d0 + dq*4) = p[i];
        }
        const int gr = ro >> 1, half = ro & 1;
        #pragma unroll
        for (int j = 0; j < 4; ++j) {               // per d: pack 8 row-bytes
            const int d = dq*4 + j;
            unsigned long long t = 0;
            #pragma unroll
            for (int i = 0; i < 8; ++i)
                t |= ((unsigned long long)((p[i] >> (8*j)) & 0xff)) << (8*i);
            *(unsigned long long*)(sT + (d*8 + (gr ^ (d & 7))) * 16 + half * 8) = t;
        }
    }
    __syncthreads();
    {
        const int d = tid >> 2, rq = tid & 3;
        unsigned char* dst = ET8 + (size_t)(d0 + d) * 32000 + r0;
        #pragma unroll
        for (int b = 0; b < 2; ++b) {
            const int gr = rq * 2 + b;
            *(uint4*)(dst + gr * 16) = *(const uint4*)(sT + (d*8 + (gr ^ (d & 7))) * 16);
        }
    }
}

// ---- K2b: gather Q -> Qb8 fp8 [2560 slots][512] (pad slots zeroed) ----
__global__ __launch_bounds__(256)
void k_qb(const float* __restrict__ q, const int* __restrict__ perm,
          unsigned char* __restrict__ Qb8) {
    const int slot = blockIdx.x * 8 + (threadIdx.x >> 5);
    const int ln = threadIdx.x & 31;
    const int tok = perm[slot];
    #pragma unroll
    for (int j = 0; j < 4; ++j) {
        const int c4 = ln + j * 32;
        int p = 0;
        if (tok >= 0) {
            float4 v = ((const float4*)q)[(size_t)tok * 128 + c4];
            p = pack_fp8x4(v.x, v.y, v.z, v.w);
        }
        ((int*)(Qb8 + (size_t)slot * Dm))[c4] = p;
    }
}

// ---- K3: S^T = E.Q^T fp8 BK=128; XCD-bound row-tiles; exp -> P8 + denoms ----
__global__ __launch_bounds__(256, 4)
void k_qk(const unsigned char* __restrict__ EB8, const unsigned char* __restrict__ Qb8,
          const int* __restrict__ meta, const int* __restrict__ perm,
          float* __restrict__ denom, unsigned char* __restrict__ P8) {
    __shared__ unsigned char sA[128 * 128];   // 16 KB, swizzled 16B granules
    __shared__ unsigned char sB[128 * 128];
    const int tid = threadIdx.x, lane = tid & 63, w = tid >> 6;
    const int g    = blockIdx.x & 7;              // XCD group
    const int rest = blockIdx.x >> 3;
    const int rt_local = rest / MAXTILES;         // 0..7
    const int tt       = rest % MAXTILES;
    const int c = g * 8 + rt_local;               // row-tile 0..63 (63: no output)
    const int slot0 = tt * TIL;
    const int b1 = meta[1], b2 = meta[2], b3 = meta[3], b4 = meta[4];
    if (slot0 >= b4) return;
    const int rank = (slot0 >= b1) + (slot0 >= b2) + (slot0 >= b3);
    const int row0 = c * 128;

    int preA[4], preB[4];
    #pragma unroll
    for (int i = 0; i < 4; ++i) {
        const int gg = w * 256 + i * 64 + lane;
        const int r = gg >> 3, cc = gg & 7, cs = cc ^ (r & 7);
        int grow = row0 + r;
        if (grow >= SEG) grow = SEG - 1;          // clamp; outputs masked
        preA[i] = grow * Dm + cs * 16;
        preB[i] = (slot0 + r) * Dm + cs * 16;
    }
    const unsigned char* EBseg = EB8 + (size_t)rank * SEG * Dm;
    const int rh = w >> 1, th = w & 1, quad = lane >> 4, l15 = lane & 15;
    const float invT = 0.04419417382415922f;   // 1/sqrt(512)

    f32x4 acc[4][4] = {};
    #pragma unroll
    for (int it = 0; it < 4; ++it) {           // K = 512, BK = 128
        const int k0 = it << 7;
        #pragma unroll
        for (int i = 0; i < 4; ++i) {
            gll16(EBseg + preA[i] + k0, sA + (w * 256 + i * 64) * 16);
            gll16(Qb8   + preB[i] + k0, sB + (w * 256 + i * 64) * 16);
        }
        __syncthreads();                       // drain staging
        #pragma unroll
        for (int ks = 0; ks < 4; ++ks) {
            const int cg = ks * 2 + (quad >> 1), ho = (quad & 1) * 8;
            long A[4], B[4];
            #pragma unroll
            for (int m = 0; m < 4; ++m) {
                const int row = rh*64 + m*16 + l15;
                A[m] = *(const long*)(sA + (row*8 + (cg ^ (row & 7)))*16 + ho);
            }
            #pragma unroll
            for (int n = 0; n < 4; ++n) {
                const int row = th*64 + n*16 + l15;
                B[n] = *(const long*)(sB + (row*8 + (cg ^ (row & 7)))*16 + ho);
            }
            #pragma unroll
            for (int m = 0; m < 4; ++m)
                #pragma unroll
                for (int n = 0; n < 4; ++n)
                    acc[m][n] = __builtin_amdgcn_mfma_f32_16x16x32_fp8_fp8(A[m], B[n], acc[m][n], 0, 0, 0);
        }
        __syncthreads();                       // compute done before overwrite
    }

    float dsum[4] = {0.f, 0.f, 0.f, 0.f};
    #pragma unroll
    for (int m = 0; m < 4; ++m) {
        const int r4 = row0 + rh*64 + m*16 + quad*4;
        if (r4 < SEG) {
            #pragma unroll
            for (int n = 0; n < 4; ++n) {
                float e0 = __expf(acc[m][n][0] * invT);
                float e1 = __expf(acc[m][n][1] * invT);
                float e2 = __expf(acc[m][n][2] * invT);
                float e3 = __expf(acc[m][n][3] * invT);
                const int slot = slot0 + th*64 + n*16 + l15;
                *(int*)(P8 + (size_t)slot * PSTR + r4) = pack_fp8x4(e0, e1, e2, e3);
                dsum[n] += e0 + e1 + e2 + e3;
            }
        } else if (r4 < PSTR) {                // zero the pad rows (k_pv tail)
            #pragma unroll
            for (int n = 0; n < 4; ++n) {
                const int slot = slot0 + th*64 + n*16 + l15;
                *(int*)(P8 + (size_t)slot * PSTR + r4) = 0;
            }
        }
    }
    #pragma unroll
    for (int n = 0; n < 4; ++n) {
        float s = dsum[n];
        s += __shfl_xor(s, 16, 64);
        s += __shfl_xor(s, 32, 64);
        if (quad == 0) {
            const int tok = perm[slot0 + th*64 + n*16 + l15];
            if (tok >= 0) atomicAdd(denom + tok, s);
        }
    }
}

// ---- K4: O^T = E^T.P^T fp8 BK=128; K-split z = XCD; bf16 partials ----
__global__ __launch_bounds__(256, 4)
void k_pv(const unsigned char* __restrict__ ET8, const unsigned char* __restrict__ P8,
          const int* __restrict__ meta, ushort* __restrict__ Oacc) {
    __shared__ unsigned char sA[128 * 128];
    __shared__ unsigned char sB[128 * 128];
    const int tid = threadIdx.x, lane = tid & 63, w = tid >> 6;
    const int z    = blockIdx.x & 7;              // K-split == XCD group
    const int rest = blockIdx.x >> 3;
    const int dt   = rest / MAXTILES;             // d-tile 0..3
    const int tt   = rest % MAXTILES;
    const int slot0 = tt * TIL;
    const int b1 = meta[1], b2 = meta[2], b3 = meta[3], b4 = meta[4];
    if (slot0 >= b4) return;
    const int rank = (slot0 >= b1) + (slot0 >= b2) + (slot0 >= b3);
    const int d0 = dt * 128;
    const int kstart = z * 1024;
    const int nit = (z == 7) ? 7 : 8;             // 7*8+7 = 63 iters -> 8064 rows

    int preA[4], preB[4];
    #pragma unroll
    for (int i = 0; i < 4; ++i) {
        const int gg = w * 256 + i * 64 + lane;
        const int r = gg >> 3, cc = gg & 7, cs = cc ^ (r & 7);
        preA[i] = (d0 + r) * 32000 + rank * SEG + cs * 16;   // v>=8000 reads x P8-pad 0
        preB[i] = (slot0 + r) * PSTR + cs * 16;
    }
    const int rh = w >> 1, th = w & 1, quad = lane >> 4, l15 = lane & 15;

    f32x4 acc[4][4] = {};
    for (int it = 0; it < nit; ++it) {
        const int k0 = kstart + (it << 7);
        #pragma unroll
        for (int i = 0; i < 4; ++i) {
            gll16(ET8 + preA[i] + k0, sA + (w * 256 + i * 64) * 16);
            gll16(P8  + preB[i] + k0, sB + (w * 256 + i * 64) * 16);
        }
        __syncthreads();
        #pragma unroll
        for (int ks = 0; ks < 4; ++ks) {
            const int cg = ks * 2 + (quad >> 1), ho = (quad & 1) * 8;
            long A[4], B[4];
            #pragma unroll
            for (int m = 0; m < 4; ++m) {
                const int row = rh*64 + m*16 + l15;
                A[m] = *(const long*)(sA + (row*8 + (cg ^ (row & 7)))*16 + ho);
            }
            #pragma unroll
            for (int n = 0; n < 4; ++n) {
                const int row = th*64 + n*16 + l15;
                B[n] = *(const long*)(sB + (row*8 + (cg ^ (row & 7)))*16 + ho);
            }
            #pragma unroll
            for (int m = 0; m < 4; ++m)
                #pragma unroll
                for (int n = 0; n < 4; ++n)
                    acc[m][n] = __builtin_amdgcn_mfma_f32_16x16x32_fp8_fp8(A[m], B[n], acc[m][n], 0, 0, 0);
        }
        __syncthreads();
    }
    ushort* Oz = Oacc + (size_t)z * Dm * MAXSLOTS;
    #pragma unroll
    for (int m = 0; m < 4; ++m) {
        const int d4 = d0 + rh*64 + m*16 + quad*4;
        #pragma unroll
        for (int n = 0; n < 4; ++n) {
            const int slot = slot0 + th*64 + n*16 + l15;
            #pragma unroll
            for (int j = 0; j < 4; ++j)
                Oz[(size_t)(d4 + j) * MAXSLOTS + slot] = f2bf(acc[m][n][j]);
        }
    }
}

// ---- K5: out[tok][d] = (sum_z Oacc[z][d][slot]) / denom + q ----
__global__ __launch_bounds__(256)
void k_final(const float* __restrict__ q, const int* __restrict__ meta,
             const int* __restrict__ perm, const float* __restrict__ denom,
             const ushort* __restrict__ Oacc, float* __restrict__ out) {
    const int d = blockIdx.x;
    const int ns = meta[4];
    for (int s = threadIdx.x; s < ns; s += 256) {
        const int tok = perm[s];
        if (tok < 0) continue;
        float v = 0.f;
        #pragma unroll
        for (int z = 0; z < 8; ++z)
            v += bf2f(Oacc[((size_t)z * Dm + d) * MAXSLOTS + s]);
        out[(size_t)tok * Dm + d] = v / denom[tok] + q[(size_t)tok * Dm + d];
    }
}

extern "C" void kernel_launch(void* const* d_in, const int* in_sizes, int n_in,
                              void* d_out, int out_size, void* d_ws, size_t ws_size,
                              hipStream_t stream) {
    const float* q   = (const float*)d_in[0];
    const int*   xr  = (const int*)d_in[1];
    const float* emb = (const float*)d_in[2];
    float* out = (float*)d_out;
    char* ws = (char*)d_ws;

    float*  denom        = (float*)(ws + WS_DENOM);
    int*    meta         = (int*)(ws + WS_META);
    int*    perm         = (int*)(ws + WS_PERM);
    unsigned char* Qb8   = (unsigned char*)(ws + WS_QB8);
    unsigned char* EB8   = (unsigned char*)(ws + WS_EB8);
    ushort* Oacc         = (ushort*)(ws + WS_OACC);
    unsigned char* ET8   = (unsigned char*)(ws + WS_ET8);
    unsigned char* P8    = (unsigned char*)(ws + WS_P8);

    k_prep<<<1, 256, 0, stream>>>(xr, meta, perm, denom);
    k_conv<<<dim3(250, 8), 256, 0, stream>>>(emb, EB8, ET8);
    k_qb<<<MAXSLOTS / 8, 256, 0, stream>>>(q, perm, Qb8);
    k_qk<<<8 * 8 * MAXTILES, 256, 0, stream>>>(EB8, Qb8, meta, perm, denom, P8);
    k_pv<<<8 * 4 * MAXTILES, 256, 0, stream>>>(ET8, P8, meta, Oacc);
    k_final<<<Dm, 256, 0, stream>>>(q, meta, perm, denom, Oacc, out);
}